// Round 1
// baseline (123.982 us; speedup 1.0000x reference)
//
#include <hip/hip_runtime.h>
#include <math.h>

#define NSV 8      // number of source views
#define NHID 64    // MLP hidden dim
#define IMG_H 544
#define IMG_W 960

__global__ __launch_bounds__(256) void sky_kernel(
    const float* __restrict__ images,   // (1,S,3,H,W)
    const float* __restrict__ extr,     // (S,4,4)
    const float* __restrict__ intr,     // (S,3,3)
    const float* __restrict__ W1,       // (3,64)
    const float* __restrict__ b1,       // (64)
    const float* __restrict__ W2,       // (64,6)
    const float* __restrict__ b2,       // (6)
    const float* __restrict__ pcd,      // (N,3)
    const float* __restrict__ lsc,      // (N,3) log-scales
    const int*   __restrict__ dsp,      // scalar downsample
    float* __restrict__ out,            // (N,6)
    int N)
{
    __shared__ float sE[NSV][12];       // extrinsics rows 0..2 (3x4)
    __shared__ float sK[NSV][9];        // Ks = intrinsics / D
    __shared__ float sW1[3][NHID];
    __shared__ float sB1[NHID];
    __shared__ float sW2[NHID][3];      // only first 3 output cols are used
    __shared__ float sB2[3];

    const int tid = threadIdx.x;

    if (tid < NSV) {
        const float ds = (float)dsp[0];
        const float* K = intr + tid * 9;
        const float* E = extr + tid * 16;
        // D = [[ds,1,ds],[1,ds,ds],[1,1,1]]; Ks = K / D
        sK[tid][0] = K[0] / ds; sK[tid][1] = K[1];      sK[tid][2] = K[2] / ds;
        sK[tid][3] = K[3];      sK[tid][4] = K[4] / ds; sK[tid][5] = K[5] / ds;
        sK[tid][6] = K[6];      sK[tid][7] = K[7];      sK[tid][8] = K[8];
        #pragma unroll
        for (int i = 0; i < 12; ++i) sE[tid][i] = E[i];
    }
    for (int i = tid; i < 3 * NHID; i += 256) sW1[i / NHID][i % NHID] = W1[i];
    if (tid < NHID) sB1[tid] = b1[tid];
    if (tid < NHID * 3) sW2[tid / 3][tid % 3] = W2[(tid / 3) * 6 + (tid % 3)];
    if (tid < 3) sB2[tid] = b2[tid];
    __syncthreads();

    const int n = blockIdx.x * 256 + tid;
    if (n >= N) return;

    const float x  = pcd[3 * n + 0];
    const float y  = pcd[3 * n + 1];
    const float zz = pcd[3 * n + 2];

    float f0 = 0.f, f1 = 0.f, f2 = 0.f;
    int cnt = 0;
    const int HW = IMG_H * IMG_W;

    #pragma unroll
    for (int s = 0; s < NSV; ++s) {
        // cam = E[:3,:] @ [x,y,z,1]   (two-stage, like the reference)
        const float cx = sE[s][0] * x + sE[s][1] * y + sE[s][2]  * zz + sE[s][3];
        const float cy = sE[s][4] * x + sE[s][5] * y + sE[s][6]  * zz + sE[s][7];
        const float cz = sE[s][8] * x + sE[s][9] * y + sE[s][10] * zz + sE[s][11];
        // uv = Ks @ cam
        const float u = sK[s][0] * cx + sK[s][1] * cy + sK[s][2] * cz;
        const float v = sK[s][3] * cx + sK[s][4] * cy + sK[s][5] * cz;
        const float w = sK[s][6] * cx + sK[s][7] * cy + sK[s][8] * cz;
        const float zs = (fabsf(w) > 1e-6f) ? w : 1e-6f;
        const float px = u / zs;
        const float py = v / zs;
        const bool m = (w > 0.001f) && (px >= 0.f) && (px <= (float)(IMG_W - 1))
                                    && (py >= 0.f) && (py <= (float)(IMG_H - 1));
        if (m) {
            int x0 = (int)floorf(px); x0 = min(max(x0, 0), IMG_W - 2);
            int y0 = (int)floorf(py); y0 = min(max(y0, 0), IMG_H - 2);
            const float wx = px - (float)x0;
            const float wy = py - (float)y0;
            const float w00 = (1.f - wx) * (1.f - wy);
            const float w01 = wx * (1.f - wy);
            const float w10 = (1.f - wx) * wy;
            const float w11 = wx * wy;
            const float* p = images + (size_t)s * 3 * HW + (size_t)y0 * IMG_W + x0;
            f0 += p[0] * w00 + p[1] * w01 + p[IMG_W] * w10 + p[IMG_W + 1] * w11;
            p += HW;
            f1 += p[0] * w00 + p[1] * w01 + p[IMG_W] * w10 + p[IMG_W + 1] * w11;
            p += HW;
            f2 += p[0] * w00 + p[1] * w01 + p[IMG_W] * w10 + p[IMG_W + 1] * w11;
            ++cnt;
        }
    }

    const float s0 = expf(lsc[3 * n + 0]);
    const float s1 = expf(lsc[3 * n + 1]);
    const float s2 = expf(lsc[3 * n + 2]);

    float o0 = 0.f, o1 = 0.f, o2 = 0.f, pm = 0.f;
    if (cnt > 0) {
        const float c = (float)cnt;
        f0 /= c; f1 /= c; f2 /= c;
        float a0 = sB2[0], a1 = sB2[1], a2 = sB2[2];
        #pragma unroll 8
        for (int j = 0; j < NHID; ++j) {
            float h = f0 * sW1[0][j] + f1 * sW1[1][j] + f2 * sW1[2][j] + sB1[j];
            h = fmaxf(h, 0.f);
            a0 += h * sW2[j][0];
            a1 += h * sW2[j][1];
            a2 += h * sW2[j][2];
        }
        o0 = tanhf(a0); o1 = tanhf(a1); o2 = tanhf(a2);
        pm = 1.f;
    }

    float* op = out + (size_t)n * 6;
    op[0] = o0;
    op[1] = o1;
    op[2] = o2;
    op[3] = s0 * pm;
    op[4] = s1 * pm;
    op[5] = s2 * pm;
}

extern "C" void kernel_launch(void* const* d_in, const int* in_sizes, int n_in,
                              void* d_out, int out_size, void* d_ws, size_t ws_size,
                              hipStream_t stream) {
    const float* images = (const float*)d_in[0];
    const float* extr   = (const float*)d_in[1];
    const float* intr   = (const float*)d_in[2];
    const float* W1     = (const float*)d_in[3];
    const float* b1     = (const float*)d_in[4];
    const float* W2     = (const float*)d_in[5];
    const float* b2     = (const float*)d_in[6];
    const float* pcd    = (const float*)d_in[7];
    const float* lsc    = (const float*)d_in[8];
    const int*   dsp    = (const int*)d_in[9];
    float* out = (float*)d_out;

    const int N = in_sizes[7] / 3;
    const int blocks = (N + 255) / 256;
    sky_kernel<<<blocks, 256, 0, stream>>>(images, extr, intr, W1, b1, W2, b2,
                                           pcd, lsc, dsp, out, N);
}